// Round 20
// baseline (1235.806 us; speedup 1.0000x reference)
//
#include <hip/hip_runtime.h>
#include <hip/hip_fp16.h>

// B=64, T=128, U=256, D_in=32, SKIP=4; dense: (64 x 32768) @ (32768 x 4096)

typedef _Float16 h8 __attribute__((ext_vector_type(8)));
typedef float f4v __attribute__((ext_vector_type(4)));

__device__ __forceinline__ float sigmoidf_(float x) {
    return 1.0f / (1.0f + __expf(-x));
}
__device__ __forceinline__ float tanhf_(float x) {
    float xc = fminf(fmaxf(x, -15.f), 15.f);
    float e = __expf(2.f * xc);
    return (e - 1.f) / (e + 1.f);
}
__device__ __forceinline__ unsigned pkh(float lo, float hi) {
    __half2 h = __halves2half2(__float2half(lo), __float2half(hi));
    return *reinterpret_cast<unsigned*>(&h);
}
__device__ __forceinline__ float2 uph(unsigned u) {
    __half2 h = *reinterpret_cast<__half2*>(&u);
    return __half22float2(h);
}

// ---------------- all weight packing + flag zeroing ----------------
__global__ __launch_bounds__(256) void packall(
    const float* __restrict__ e_rk, const float* __restrict__ d_rk,
    const float* __restrict__ d_k,  const float* __restrict__ e_k,
    const float* __restrict__ e_k2, const float* __restrict__ d_k2,
    float4* __restrict__ rk4e, float4* __restrict__ rk4d,
    float4* __restrict__ dk4,  float4* __restrict__ ek4,
    unsigned* __restrict__ kh2e, unsigned* __restrict__ kh2d,
    unsigned* __restrict__ flags)
{
    const int bx = blockIdx.x, v = threadIdx.x;
    if (bx < 800) {
        const float* src; float4* dst; int row;
        if (bx < 256)      { src = e_rk; dst = rk4e; row = bx; }
        else if (bx < 512) { src = d_rk; dst = rk4d; row = bx - 256; }
        else if (bx < 768) { src = d_k;  dst = dk4;  row = bx - 512; }
        else               { src = e_k;  dst = ek4;  row = bx - 768; }
        const float* s = src + (size_t)row * 1024;
        dst[row * 256 + v] = make_float4(s[v], s[256 + v], s[512 + v], s[768 + v]);
    } else if (bx < 928) {
        const int u2 = bx - 800;   // 0..127
        kh2e[u2 * 256 + v] = pkh(e_k2[(2 * u2) * 256 + v], e_k2[(2 * u2 + 1) * 256 + v]);
        kh2d[u2 * 256 + v] = pkh(d_k2[(2 * u2) * 256 + v], d_k2[(2 * u2 + 1) * 256 + v]);
    } else {
        flags[v] = 0u;             // re-zeroed every launch (graph-safe)
    }
}

// ---------------- enc xW GEMM: K=32 rows gathered from X[:,0] ----------------
__global__ __launch_bounds__(256) void xw_gemm_enc(
    const float*  __restrict__ X,
    const float4* __restrict__ ek4,
    const float*  __restrict__ bias,
    float4* __restrict__ xWp)
{
    const int v = threadIdx.x;
    const int r0 = blockIdx.x * 16;
    __shared__ float se[16][32];

    #pragma unroll
    for (int p = 0; p < 2; ++p) {
        int idx = p * 256 + v;
        int rr = idx >> 5, d = idx & 31;
        int R = r0 + rr, b = R >> 7, t = R & 127;
        se[rr][d] = X[((size_t)b * 129 * 128 + t) * 32 + d];   // X[b,0,t,d]
    }
    __syncthreads();

    float4 bv = make_float4(bias[v], bias[256 + v], bias[512 + v], bias[768 + v]);
    float4 acc[16];
    #pragma unroll
    for (int rr = 0; rr < 16; ++rr) acc[rr] = bv;

    #pragma unroll
    for (int u = 0; u < 32; ++u) {
        float4 w = ek4[u * 256 + v];
        #pragma unroll
        for (int rr = 0; rr < 16; ++rr) {
            float s = se[rr][u];
            acc[rr].x += s * w.x; acc[rr].y += s * w.y;
            acc[rr].z += s * w.z; acc[rr].w += s * w.w;
        }
    }
    #pragma unroll
    for (int rr = 0; rr < 16; ++rr)
        xWp[(size_t)(r0 + rr) * 256 + v] = acc[rr];
}

// ---------------- dec xW GEMM: 32 rows/block, 512 threads ----------------
__global__ __launch_bounds__(512) void xw_gemm_dec(
    const float*  __restrict__ SE,
    const float4* __restrict__ dk4,
    const float*  __restrict__ bias,
    float4* __restrict__ xWp)
{
    const int tid = threadIdx.x;
    const int v = tid & 255;
    const int hh = tid >> 8;               // 0/1
    const int rbase = blockIdx.x * 32;
    __shared__ float se[32][256];

    for (int i = tid; i < 8192; i += 512) {
        int rr = i >> 8, c = i & 255;
        se[rr][c] = SE[(size_t)(rbase + rr) * 256 + c];
    }
    __syncthreads();

    float4 bv = make_float4(bias[v], bias[256 + v], bias[512 + v], bias[768 + v]);
    float4 acc[16];
    #pragma unroll
    for (int rr = 0; rr < 16; ++rr) acc[rr] = bv;

    #pragma unroll 8
    for (int u = 0; u < 256; ++u) {
        float4 w = dk4[u * 256 + v];
        #pragma unroll
        for (int rr = 0; rr < 16; ++rr) {
            float s = se[hh * 16 + rr][u];
            acc[rr].x += s * w.x; acc[rr].y += s * w.y;
            acc[rr].z += s * w.z; acc[rr].w += s * w.w;
        }
    }
    #pragma unroll
    for (int rr = 0; rr < 16; ++rr)
        xWp[(size_t)(rbase + hh * 16 + rr) * 256 + v] = acc[rr];
}

// ---------------- skip-LSTM recurrence: rec9 minus the redundant 4th barrier ----------------
// Barrier-D removal safety: wave0 reaches next step's barrier A only after finish(t)
// (program order), so A orders finish writes for all GEMV(t+1) readers; pA overwrite at
// GEMV(t+1) is after barrier B > A > finish(t)'s reads; stage(t+1) pq writes are
// region-disjoint from finish(t)'s. Inter-block EX/flag protocol untouched.
__global__ __launch_bounds__(1024, 4) void rec12(
    const float4*   __restrict__ xW,
    const float4*   __restrict__ rk4,
    const unsigned* __restrict__ kh2,
    const float*    __restrict__ bias2,
    const float*    __restrict__ s0p,
    float* __restrict__ out,
    float* __restrict__ EX,             // [2][64][4][320] floats
    unsigned* __restrict__ flags,       // [64][4]
    unsigned fbase)
{
    const int b     = blockIdx.x & 63;
    const int slice = blockIdx.x >> 6;
    const int voff  = slice * 64;
    const int tid   = threadIdx.x;
    const int us    = tid >> 6;
    const int vl    = tid & 63;
    const int v     = voff + vl;

    __shared__ float4 wres[128][64];
    __shared__ float4 pA[16][64];
    __shared__ float  pS[16][64];
    __shared__ float4 h4[256];
    __shared__ float  pq[4][256];

    for (int i = tid; i < 8192; i += 1024) {
        int r = i >> 6, vv = i & 63;
        int cc = r >> 3, j = r & 7;
        wres[r][vv] = rk4[(cc * 16 + j) * 256 + voff + vv];
    }
    float4 wreg[8];
    unsigned kreg[8];
    {
        const float4*   wp = rk4 + (us * 16 + 8) * 256 + v;
        const unsigned* kp = kh2 + (us * 8) * 256 + v;
        #pragma unroll
        for (int j = 0; j < 8; ++j) wreg[j] = wp[j * 256];
        #pragma unroll
        for (int j = 0; j < 8; ++j) kreg[j] = kp[j * 256];
    }
    if (tid < 256) {
        h4[tid] = make_float4(0.f, 0.f, 0.f, 0.f);
        pq[0][tid] = 0.f; pq[1][tid] = 0.f; pq[2][tid] = 0.f; pq[3][tid] = 0.f;
    }
    float cst = 0.f;
    const float s0 = s0p[0];
    const float b2 = bias2[voff + vl];
    unsigned* mflag = flags + b * 4 + slice;
    __syncthreads();

    for (int t = 0; t < 128; ++t) {
        float4 xa = make_float4(0.f, 0.f, 0.f, 0.f);
        if (tid < 64) xa = xW[((size_t)b * 128 + t) * 256 + voff + tid];
        if (t > 0 && tid < 3) {
            int ps = tid + (tid >= slice ? 1 : 0);
            const unsigned* pf = flags + b * 4 + ps;
            while (__hip_atomic_load(pf, __ATOMIC_RELAXED, __HIP_MEMORY_SCOPE_AGENT) < fbase + (unsigned)t)
                __builtin_amdgcn_s_sleep(2);
        }
        __syncthreads();   // A: partners ready + finish(t-1) writes visible
        if (t > 0) {
            const int sp = (t + 1) & 1;
            if (tid < 480) {
                int pi = tid / 160;
                int j  = tid - pi * 160;
                int ps = pi + (pi >= slice ? 1 : 0);
                const unsigned long long* src = (const unsigned long long*)
                    (EX + (((size_t)sp * 64 + b) * 4 + ps) * 320);
                unsigned long long d = __hip_atomic_load(src + j, __ATOMIC_RELAXED, __HIP_MEMORY_SCOPE_AGENT);
                if (j < 128) {
                    reinterpret_cast<unsigned long long*>(&h4[ps * 64])[j] = d;
                } else {
                    int k = j - 128;
                    union { unsigned long long u; float f[2]; } cv; cv.u = d;
                    pq[(t + 3) & 3][ps * 64 + 2 * k]     = cv.f[0];
                    pq[(t + 3) & 3][ps * 64 + 2 * k + 1] = cv.f[1];
                }
            }
        }
        __syncthreads();   // B: staged state visible

        float ai = 0.f, af = 0.f, acg = 0.f, ao = 0.f, as = 0.f;
        const int slot = t & 3;
        #pragma unroll
        for (int j = 0; j < 8; ++j) {
            float4 w = wres[us * 8 + j][vl];
            float4 g = h4[us * 16 + j];
            ai += g.x * w.x; af += g.y * w.y; acg += g.z * w.z; ao += g.w * w.w;
        }
        #pragma unroll
        for (int j = 0; j < 8; ++j) {
            float4 w = wreg[j];
            float4 g = h4[us * 16 + 8 + j];
            ai += g.x * w.x; af += g.y * w.y; acg += g.z * w.z; ao += g.w * w.w;
        }
        #pragma unroll
        for (int j = 0; j < 8; ++j) {
            float2 kk = uph(kreg[j]);
            as += pq[slot][us * 16 + 2 * j] * kk.x + pq[slot][us * 16 + 2 * j + 1] * kk.y;
        }
        pA[us][vl] = make_float4(ai, af, acg, ao);
        pS[us][vl] = as;
        __syncthreads();   // C: pA/pS complete

        if (tid < 64) {
            float4 A = pA[0][vl];
            float  S = pS[0][vl];
            #pragma unroll
            for (int cc = 1; cc < 16; ++cc) {
                float4 q = pA[cc][vl];
                A.x += q.x; A.y += q.y; A.z += q.z; A.w += q.w;
                S += pS[cc][vl];
            }
            float gi = sigmoidf_(xa.x + A.x);
            float gf = sigmoidf_(xa.y + A.y);
            float cb = tanhf_(xa.z + A.z);
            cst = gf * cst + gi * cb;
            float go = sigmoidf_(xa.w + A.w);
            float hh = go * tanhf_(cst);
            float hs = sigmoidf_(S + b2);
            float hf = s0 * hh + (1.f - s0) * hs;
            h4[voff + vl] = make_float4(gi, gf, cst, go);
            pq[slot][voff + vl] = hf;
            out[((size_t)b * 128 + t) * 256 + voff + vl] = hf;
            float* dst = EX + (((size_t)(t & 1) * 64 + b) * 4 + slice) * 320;
            union { float4 f4; unsigned long long u[2]; } gv;
            gv.f4 = make_float4(gi, gf, cst, go);
            __hip_atomic_store((unsigned long long*)dst + 2 * vl,     gv.u[0], __ATOMIC_RELAXED, __HIP_MEMORY_SCOPE_AGENT);
            __hip_atomic_store((unsigned long long*)dst + 2 * vl + 1, gv.u[1], __ATOMIC_RELAXED, __HIP_MEMORY_SCOPE_AGENT);
            __hip_atomic_store(dst + 256 + vl, hf, __ATOMIC_RELAXED, __HIP_MEMORY_SCOPE_AGENT);
            asm volatile("s_waitcnt vmcnt(0)" ::: "memory");   // publishes drain before flag
            if (tid == 0)
                __hip_atomic_store(mflag, fbase + (unsigned)(t + 1), __ATOMIC_RELAXED, __HIP_MEMORY_SCOPE_AGENT);
        }
        // (barrier D removed — next step's barrier A provides the ordering)
    }
}

// ---------------- SD fp32 -> fp16 ----------------
__global__ __launch_bounds__(256) void cvt_sd(const float* __restrict__ SD, _Float16* __restrict__ SDh)
{
    const int i = (blockIdx.x * 256 + threadIdx.x) * 8;
    float4 a = *reinterpret_cast<const float4*>(SD + i);
    float4 b = *reinterpret_cast<const float4*>(SD + i + 4);
    h8 h;
    h[0] = (_Float16)a.x; h[1] = (_Float16)a.y; h[2] = (_Float16)a.z; h[3] = (_Float16)a.w;
    h[4] = (_Float16)b.x; h[5] = (_Float16)b.y; h[6] = (_Float16)b.z; h[7] = (_Float16)b.w;
    *reinterpret_cast<h8*>(SDh + i) = h;
}

// ---------------- dense via MFMA fp16, float4-staged B conversion ----------------
// grid 256: kc = bid>>6 (split-K 4), nb = bid&63 (64-col tiles). Block 256 thr = 4 waves.
// Stage: thread (rq,nq) loads 4 float4 rows of dw, packs row-pairs -> Bt[n][k2] half2.
// MFMA part identical to round-19 (verified layout).
__global__ __launch_bounds__(256, 4) void mfma_dense(
    const _Float16* __restrict__ SDh,   // (64 x 32768)
    const float*    __restrict__ dw,    // (32768 x 4096)
    float* __restrict__ P)              // (4 x 64 x 4096)
{
    const int nb  = blockIdx.x & 63;
    const int kc  = blockIdx.x >> 6;    // 0..3
    const int n0  = nb * 64;
    const int tid = threadIdx.x;
    const int w   = tid >> 6;           // wave 0..3
    const int l   = tid & 63;
    const int ar  = l & 15;
    const int ko8 = (l >> 4) * 8;       // k-offset (halfs) within a 32-k window
    const int rq  = tid >> 4;           // 0..15 row-quad
    const int nq  = tid & 15;           // 0..15 n-quad

    __shared__ unsigned Bt[64][36];     // [n][k2] half2-packed (32 k2 + pad)

    f4v acc[4] = {{0.f,0.f,0.f,0.f},{0.f,0.f,0.f,0.f},{0.f,0.f,0.f,0.f},{0.f,0.f,0.f,0.f}};

    for (int kk = 0; kk < 128; ++kk) {
        const int kg = kc * 8192 + kk * 64;
        // stage 64k x 64n panel: 4 float4 loads per thread, pack row-pairs
        {
            const float* base = dw + (size_t)(kg + rq * 4) * 4096 + n0 + nq * 4;
            float4 r0 = *reinterpret_cast<const float4*>(base);
            float4 r1 = *reinterpret_cast<const float4*>(base + 4096);
            float4 r2 = *reinterpret_cast<const float4*>(base + 2 * 4096);
            float4 r3 = *reinterpret_cast<const float4*>(base + 3 * 4096);
            const int k2a = rq * 2, k2b = rq * 2 + 1;
            Bt[nq * 4 + 0][k2a] = pkh(r0.x, r1.x);
            Bt[nq * 4 + 1][k2a] = pkh(r0.y, r1.y);
            Bt[nq * 4 + 2][k2a] = pkh(r0.z, r1.z);
            Bt[nq * 4 + 3][k2a] = pkh(r0.w, r1.w);
            Bt[nq * 4 + 0][k2b] = pkh(r2.x, r3.x);
            Bt[nq * 4 + 1][k2b] = pkh(r2.y, r3.y);
            Bt[nq * 4 + 2][k2b] = pkh(r2.z, r3.z);
            Bt[nq * 4 + 3][k2b] = pkh(r2.w, r3.w);
        }
        __syncthreads();
        #pragma unroll
        for (int hs = 0; hs < 2; ++hs) {
            const int kw = kg + hs * 32;
            h8 bf = *reinterpret_cast<const h8*>(
                      reinterpret_cast<const _Float16*>(&Bt[16 * w + ar][0]) + hs * 32 + ko8);
            #pragma unroll
            for (int mt = 0; mt < 4; ++mt) {
                h8 af = *reinterpret_cast<const h8*>(
                          SDh + (size_t)(mt * 16 + ar) * 32768 + kw + ko8);
                acc[mt] = __builtin_amdgcn_mfma_f32_16x16x32_f16(af, bf, acc[mt], 0, 0, 0);
            }
        }
        __syncthreads();
    }
    #pragma unroll
    for (int mt = 0; mt < 4; ++mt) {
        #pragma unroll
        for (int r = 0; r < 4; ++r) {
            P[(size_t)(kc * 64 + mt * 16 + (l >> 4) * 4 + r) * 4096 + n0 + 16 * w + ar] = acc[mt][r];
        }
    }
}

// ---------------- reduce partials + bias + Z2 ----------------
__global__ __launch_bounds__(256) void reduce_z2(
    const float* __restrict__ P,
    const float* __restrict__ db,
    const float* __restrict__ X,
    const float* __restrict__ fw,
    const float* __restrict__ fbp,
    float* __restrict__ out)
{
    const int o4 = blockIdx.x * 256 + threadIdx.x;   // 0..65535
    const int b  = o4 >> 10;
    const int j4 = o4 & 1023;
    const int j0 = j4 * 4;
    const int i  = j0 >> 5;
    const int m  = j0 & 31;

    float4 acc = *reinterpret_cast<const float4*>(db + j0);
    #pragma unroll
    for (int kc = 0; kc < 4; ++kc) {
        float4 p = *reinterpret_cast<const float4*>(P + (size_t)(kc * 64 + b) * 4096 + j0);
        acc.x += p.x; acc.y += p.y; acc.z += p.z; acc.w += p.w;
    }

    const float* xp = X + ((size_t)(b * 129 + 1 + i) * 128) * 32 + m;
    #pragma unroll 8
    for (int s = 0; s < 128; ++s) {
        float4 xv = *reinterpret_cast<const float4*>(xp + (size_t)s * 32);
        float w = fw[s];
        acc.x += w * xv.x; acc.y += w * xv.y; acc.z += w * xv.z; acc.w += w * xv.w;
    }
    const float fb = fbp[0];
    acc.x += fb; acc.y += fb; acc.z += fb; acc.w += fb;
    *reinterpret_cast<float4*>(out + (size_t)o4 * 4) = acc;
}

extern "C" void kernel_launch(void* const* d_in, const int* in_sizes, int n_in,
                              void* d_out, int out_size, void* d_ws, size_t ws_size,
                              hipStream_t stream) {
    const float* X    = (const float*)d_in[0];
    const float* e_k  = (const float*)d_in[1];
    const float* e_rk = (const float*)d_in[2];
    const float* e_k2 = (const float*)d_in[3];
    const float* e_b  = (const float*)d_in[4];
    const float* e_b2 = (const float*)d_in[5];
    const float* e_s0 = (const float*)d_in[6];
    const float* d_k  = (const float*)d_in[7];
    const float* d_rk = (const float*)d_in[8];
    const float* d_k2 = (const float*)d_in[9];
    const float* d_b  = (const float*)d_in[10];
    const float* d_b2 = (const float*)d_in[11];
    const float* d_s0 = (const float*)d_in[12];
    const float* dw   = (const float*)d_in[13];
    const float* db   = (const float*)d_in[14];
    const float* fw   = (const float*)d_in[15];
    const float* fb   = (const float*)d_in[16];

    float* ws = (float*)d_ws;
    // rk4e 0 | rk4d 262144 | dk4 524288 | ek4 786432 | kh2e 819200 | kh2d 851968
    // EX 884736 (+327680) | flags 1212416 | xW 1310720 (8M; reused: P 1M @1310720,
    // SDh 1M-floats @5505024 — xW dead after rec12-dec) | SE 9699328 (2M) | SD 11796480 (2M)
    float4*   rk4e  = (float4*)(ws);
    float4*   rk4d  = (float4*)(ws + 262144);
    float4*   dk4   = (float4*)(ws + 524288);
    float4*   ek4   = (float4*)(ws + 786432);
    unsigned* kh2e  = (unsigned*)(ws + 819200);
    unsigned* kh2d  = (unsigned*)(ws + 851968);
    float*    EX    = ws + 884736;
    unsigned* flags = (unsigned*)(ws + 1212416);
    float*    xW    = ws + 1310720;
    float*    SE    = ws + 9699328;
    float*    SD    = ws + 11796480;

    float*     P   = xW;                          // 4*64*4096 = 1M floats
    _Float16*  SDh = (_Float16*)(ws + 5505024);   // 2M halfs

    hipLaunchKernelGGL(packall, dim3(929), dim3(256), 0, stream,
                       e_rk, d_rk, d_k, e_k, e_k2, d_k2,
                       rk4e, rk4d, dk4, ek4, kh2e, kh2d, flags);
    hipLaunchKernelGGL(xw_gemm_enc, dim3(512), dim3(256), 0, stream,
                       X, ek4, e_b, (float4*)xW);
    hipLaunchKernelGGL(rec12, dim3(256), dim3(1024), 0, stream,
                       (const float4*)xW, rk4e, kh2e, e_b2, e_s0, SE, EX, flags, 0u);
    hipLaunchKernelGGL(xw_gemm_dec, dim3(256), dim3(512), 0, stream,
                       SE, dk4, d_b, (float4*)xW);
    hipLaunchKernelGGL(rec12, dim3(256), dim3(1024), 0, stream,
                       (const float4*)xW, rk4d, kh2d, d_b2, d_s0, SD, EX, flags, 128u);
    hipLaunchKernelGGL(cvt_sd, dim3(1024), dim3(256), 0, stream, SD, SDh);
    hipLaunchKernelGGL(mfma_dense, dim3(256), dim3(256), 0, stream, SDh, dw, P);
    hipLaunchKernelGGL(reduce_z2, dim3(256), dim3(256), 0, stream,
                       P, db, X, fw, fb, (float*)d_out);
}

// Round 21
// 1095.659 us; speedup vs baseline: 1.1279x; 1.1279x over previous
//
#include <hip/hip_runtime.h>
#include <hip/hip_fp16.h>

// B=64, T=128, U=256, D_in=32, SKIP=4; dense: (64 x 32768) @ (32768 x 4096)

typedef _Float16 h8 __attribute__((ext_vector_type(8)));
typedef float f4v __attribute__((ext_vector_type(4)));

__device__ __forceinline__ float sigmoidf_(float x) {
    return 1.0f / (1.0f + __expf(-x));
}
__device__ __forceinline__ float tanhf_(float x) {
    float xc = fminf(fmaxf(x, -15.f), 15.f);
    float e = __expf(2.f * xc);
    return (e - 1.f) / (e + 1.f);
}
__device__ __forceinline__ unsigned pkh(float lo, float hi) {
    __half2 h = __halves2half2(__float2half(lo), __float2half(hi));
    return *reinterpret_cast<unsigned*>(&h);
}
__device__ __forceinline__ float2 uph(unsigned u) {
    __half2 h = *reinterpret_cast<__half2*>(&u);
    return __half22float2(h);
}

// ---------------- all weight packing + flag zeroing ----------------
__global__ __launch_bounds__(256) void packall(
    const float* __restrict__ e_rk, const float* __restrict__ d_rk,
    const float* __restrict__ d_k,  const float* __restrict__ e_k,
    const float* __restrict__ e_k2, const float* __restrict__ d_k2,
    float4* __restrict__ rk4e, float4* __restrict__ rk4d,
    float4* __restrict__ dk4,  float4* __restrict__ ek4,
    unsigned* __restrict__ kh2e, unsigned* __restrict__ kh2d,
    unsigned* __restrict__ flags)
{
    const int bx = blockIdx.x, v = threadIdx.x;
    if (bx < 800) {
        const float* src; float4* dst; int row;
        if (bx < 256)      { src = e_rk; dst = rk4e; row = bx; }
        else if (bx < 512) { src = d_rk; dst = rk4d; row = bx - 256; }
        else if (bx < 768) { src = d_k;  dst = dk4;  row = bx - 512; }
        else               { src = e_k;  dst = ek4;  row = bx - 768; }
        const float* s = src + (size_t)row * 1024;
        dst[row * 256 + v] = make_float4(s[v], s[256 + v], s[512 + v], s[768 + v]);
    } else if (bx < 928) {
        const int u2 = bx - 800;   // 0..127
        kh2e[u2 * 256 + v] = pkh(e_k2[(2 * u2) * 256 + v], e_k2[(2 * u2 + 1) * 256 + v]);
        kh2d[u2 * 256 + v] = pkh(d_k2[(2 * u2) * 256 + v], d_k2[(2 * u2 + 1) * 256 + v]);
    } else {
        flags[v] = 0u;             // re-zeroed every launch (graph-safe)
    }
}

// ---------------- enc xW GEMM: K=32 rows gathered from X[:,0] ----------------
__global__ __launch_bounds__(256) void xw_gemm_enc(
    const float*  __restrict__ X,
    const float4* __restrict__ ek4,
    const float*  __restrict__ bias,
    float4* __restrict__ xWp)
{
    const int v = threadIdx.x;
    const int r0 = blockIdx.x * 16;
    __shared__ float se[16][32];

    #pragma unroll
    for (int p = 0; p < 2; ++p) {
        int idx = p * 256 + v;
        int rr = idx >> 5, d = idx & 31;
        int R = r0 + rr, b = R >> 7, t = R & 127;
        se[rr][d] = X[((size_t)b * 129 * 128 + t) * 32 + d];   // X[b,0,t,d]
    }
    __syncthreads();

    float4 bv = make_float4(bias[v], bias[256 + v], bias[512 + v], bias[768 + v]);
    float4 acc[16];
    #pragma unroll
    for (int rr = 0; rr < 16; ++rr) acc[rr] = bv;

    #pragma unroll
    for (int u = 0; u < 32; ++u) {
        float4 w = ek4[u * 256 + v];
        #pragma unroll
        for (int rr = 0; rr < 16; ++rr) {
            float s = se[rr][u];
            acc[rr].x += s * w.x; acc[rr].y += s * w.y;
            acc[rr].z += s * w.z; acc[rr].w += s * w.w;
        }
    }
    #pragma unroll
    for (int rr = 0; rr < 16; ++rr)
        xWp[(size_t)(r0 + rr) * 256 + v] = acc[rr];
}

// ---------------- dec xW GEMM: 32 rows/block, 512 threads ----------------
__global__ __launch_bounds__(512) void xw_gemm_dec(
    const float*  __restrict__ SE,
    const float4* __restrict__ dk4,
    const float*  __restrict__ bias,
    float4* __restrict__ xWp)
{
    const int tid = threadIdx.x;
    const int v = tid & 255;
    const int hh = tid >> 8;               // 0/1
    const int rbase = blockIdx.x * 32;
    __shared__ float se[32][256];

    for (int i = tid; i < 8192; i += 512) {
        int rr = i >> 8, c = i & 255;
        se[rr][c] = SE[(size_t)(rbase + rr) * 256 + c];
    }
    __syncthreads();

    float4 bv = make_float4(bias[v], bias[256 + v], bias[512 + v], bias[768 + v]);
    float4 acc[16];
    #pragma unroll
    for (int rr = 0; rr < 16; ++rr) acc[rr] = bv;

    #pragma unroll 8
    for (int u = 0; u < 256; ++u) {
        float4 w = dk4[u * 256 + v];
        #pragma unroll
        for (int rr = 0; rr < 16; ++rr) {
            float s = se[hh * 16 + rr][u];
            acc[rr].x += s * w.x; acc[rr].y += s * w.y;
            acc[rr].z += s * w.z; acc[rr].w += s * w.w;
        }
    }
    #pragma unroll
    for (int rr = 0; rr < 16; ++rr)
        xWp[(size_t)(rbase + hh * 16 + rr) * 256 + v] = acc[rr];
}

// ---------------- skip-LSTM recurrence (rec9, round-15 proven, unchanged) ----------------
__global__ __launch_bounds__(1024, 4) void rec9(
    const float4*   __restrict__ xW,
    const float4*   __restrict__ rk4,
    const unsigned* __restrict__ kh2,
    const float*    __restrict__ bias2,
    const float*    __restrict__ s0p,
    float* __restrict__ out,
    float* __restrict__ EX,             // [2][64][4][320] floats
    unsigned* __restrict__ flags,       // [64][4]
    unsigned fbase)
{
    const int b     = blockIdx.x & 63;
    const int slice = blockIdx.x >> 6;
    const int voff  = slice * 64;
    const int tid   = threadIdx.x;
    const int us    = tid >> 6;
    const int vl    = tid & 63;
    const int v     = voff + vl;

    __shared__ float4 wres[128][64];
    __shared__ float4 pA[16][64];
    __shared__ float  pS[16][64];
    __shared__ float4 h4[256];
    __shared__ float  pq[4][256];

    for (int i = tid; i < 8192; i += 1024) {
        int r = i >> 6, vv = i & 63;
        int cc = r >> 3, j = r & 7;
        wres[r][vv] = rk4[(cc * 16 + j) * 256 + voff + vv];
    }
    float4 wreg[8];
    unsigned kreg[8];
    {
        const float4*   wp = rk4 + (us * 16 + 8) * 256 + v;
        const unsigned* kp = kh2 + (us * 8) * 256 + v;
        #pragma unroll
        for (int j = 0; j < 8; ++j) wreg[j] = wp[j * 256];
        #pragma unroll
        for (int j = 0; j < 8; ++j) kreg[j] = kp[j * 256];
    }
    if (tid < 256) {
        h4[tid] = make_float4(0.f, 0.f, 0.f, 0.f);
        pq[0][tid] = 0.f; pq[1][tid] = 0.f; pq[2][tid] = 0.f; pq[3][tid] = 0.f;
    }
    float cst = 0.f;
    const float s0 = s0p[0];
    const float b2 = bias2[voff + vl];
    unsigned* mflag = flags + b * 4 + slice;
    __syncthreads();

    for (int t = 0; t < 128; ++t) {
        float4 xa = make_float4(0.f, 0.f, 0.f, 0.f);
        if (tid < 64) xa = xW[((size_t)b * 128 + t) * 256 + voff + tid];
        if (t > 0 && tid < 3) {
            int ps = tid + (tid >= slice ? 1 : 0);
            const unsigned* pf = flags + b * 4 + ps;
            while (__hip_atomic_load(pf, __ATOMIC_RELAXED, __HIP_MEMORY_SCOPE_AGENT) < fbase + (unsigned)t)
                __builtin_amdgcn_s_sleep(2);
        }
        __syncthreads();
        if (t > 0) {
            const int sp = (t + 1) & 1;
            if (tid < 480) {
                int pi = tid / 160;
                int j  = tid - pi * 160;
                int ps = pi + (pi >= slice ? 1 : 0);
                const unsigned long long* src = (const unsigned long long*)
                    (EX + (((size_t)sp * 64 + b) * 4 + ps) * 320);
                unsigned long long d = __hip_atomic_load(src + j, __ATOMIC_RELAXED, __HIP_MEMORY_SCOPE_AGENT);
                if (j < 128) {
                    reinterpret_cast<unsigned long long*>(&h4[ps * 64])[j] = d;
                } else {
                    int k = j - 128;
                    union { unsigned long long u; float f[2]; } cv; cv.u = d;
                    pq[(t + 3) & 3][ps * 64 + 2 * k]     = cv.f[0];
                    pq[(t + 3) & 3][ps * 64 + 2 * k + 1] = cv.f[1];
                }
            }
        }
        __syncthreads();

        float ai = 0.f, af = 0.f, acg = 0.f, ao = 0.f, as = 0.f;
        const int slot = t & 3;
        #pragma unroll
        for (int j = 0; j < 8; ++j) {
            float4 w = wres[us * 8 + j][vl];
            float4 g = h4[us * 16 + j];
            ai += g.x * w.x; af += g.y * w.y; acg += g.z * w.z; ao += g.w * w.w;
        }
        #pragma unroll
        for (int j = 0; j < 8; ++j) {
            float4 w = wreg[j];
            float4 g = h4[us * 16 + 8 + j];
            ai += g.x * w.x; af += g.y * w.y; acg += g.z * w.z; ao += g.w * w.w;
        }
        #pragma unroll
        for (int j = 0; j < 8; ++j) {
            float2 kk = uph(kreg[j]);
            as += pq[slot][us * 16 + 2 * j] * kk.x + pq[slot][us * 16 + 2 * j + 1] * kk.y;
        }
        pA[us][vl] = make_float4(ai, af, acg, ao);
        pS[us][vl] = as;
        __syncthreads();

        if (tid < 64) {
            float4 A = pA[0][vl];
            float  S = pS[0][vl];
            #pragma unroll
            for (int cc = 1; cc < 16; ++cc) {
                float4 q = pA[cc][vl];
                A.x += q.x; A.y += q.y; A.z += q.z; A.w += q.w;
                S += pS[cc][vl];
            }
            float gi = sigmoidf_(xa.x + A.x);
            float gf = sigmoidf_(xa.y + A.y);
            float cb = tanhf_(xa.z + A.z);
            cst = gf * cst + gi * cb;
            float go = sigmoidf_(xa.w + A.w);
            float hh = go * tanhf_(cst);
            float hs = sigmoidf_(S + b2);
            float hf = s0 * hh + (1.f - s0) * hs;
            h4[voff + vl] = make_float4(gi, gf, cst, go);
            pq[slot][voff + vl] = hf;
            out[((size_t)b * 128 + t) * 256 + voff + vl] = hf;
            float* dst = EX + (((size_t)(t & 1) * 64 + b) * 4 + slice) * 320;
            union { float4 f4; unsigned long long u[2]; } gv;
            gv.f4 = make_float4(gi, gf, cst, go);
            __hip_atomic_store((unsigned long long*)dst + 2 * vl,     gv.u[0], __ATOMIC_RELAXED, __HIP_MEMORY_SCOPE_AGENT);
            __hip_atomic_store((unsigned long long*)dst + 2 * vl + 1, gv.u[1], __ATOMIC_RELAXED, __HIP_MEMORY_SCOPE_AGENT);
            __hip_atomic_store(dst + 256 + vl, hf, __ATOMIC_RELAXED, __HIP_MEMORY_SCOPE_AGENT);
        }
        __syncthreads();
        if (tid == 0)
            __hip_atomic_store(mflag, fbase + (unsigned)(t + 1), __ATOMIC_RELAXED, __HIP_MEMORY_SCOPE_AGENT);
    }
}

// ---------------- SD fp32 -> fp16 ----------------
__global__ __launch_bounds__(256) void cvt_sd(const float* __restrict__ SD, _Float16* __restrict__ SDh)
{
    const int i = (blockIdx.x * 256 + threadIdx.x) * 8;
    float4 a = *reinterpret_cast<const float4*>(SD + i);
    float4 b = *reinterpret_cast<const float4*>(SD + i + 4);
    h8 h;
    h[0] = (_Float16)a.x; h[1] = (_Float16)a.y; h[2] = (_Float16)a.z; h[3] = (_Float16)a.w;
    h[4] = (_Float16)b.x; h[5] = (_Float16)b.y; h[6] = (_Float16)b.z; h[7] = (_Float16)b.w;
    *reinterpret_cast<h8*>(SDh + i) = h;
}

// ---------------- dense via MFMA fp16: split-K 8 (512 blocks, 2/CU) ----------------
// grid 512: kc = bid>>6 (0..7, 4096 k-rows each), nb = bid&63. Block 256 thr = 4 waves.
// Stage: thread (rq,nq) loads 4 float4 rows of dw, packs row-pairs -> Bt[n][k2] half2.
__global__ __launch_bounds__(256, 4) void mfma_dense(
    const _Float16* __restrict__ SDh,   // (64 x 32768)
    const float*    __restrict__ dw,    // (32768 x 4096)
    float* __restrict__ P)              // (8 x 64 x 4096)
{
    const int nb  = blockIdx.x & 63;
    const int kc  = blockIdx.x >> 6;    // 0..7
    const int n0  = nb * 64;
    const int tid = threadIdx.x;
    const int w   = tid >> 6;           // wave 0..3
    const int l   = tid & 63;
    const int ar  = l & 15;
    const int ko8 = (l >> 4) * 8;       // k-offset (halfs) within a 32-k window
    const int rq  = tid >> 4;           // 0..15 row-quad
    const int nq  = tid & 15;           // 0..15 n-quad

    __shared__ unsigned Bt[64][36];     // [n][k2] half2-packed (32 k2 + pad)

    f4v acc[4] = {{0.f,0.f,0.f,0.f},{0.f,0.f,0.f,0.f},{0.f,0.f,0.f,0.f},{0.f,0.f,0.f,0.f}};

    for (int kk = 0; kk < 64; ++kk) {
        const int kg = kc * 4096 + kk * 64;
        // stage 64k x 64n panel: 4 float4 loads per thread, pack row-pairs
        {
            const float* base = dw + (size_t)(kg + rq * 4) * 4096 + n0 + nq * 4;
            float4 r0 = *reinterpret_cast<const float4*>(base);
            float4 r1 = *reinterpret_cast<const float4*>(base + 4096);
            float4 r2 = *reinterpret_cast<const float4*>(base + 2 * 4096);
            float4 r3 = *reinterpret_cast<const float4*>(base + 3 * 4096);
            const int k2a = rq * 2, k2b = rq * 2 + 1;
            Bt[nq * 4 + 0][k2a] = pkh(r0.x, r1.x);
            Bt[nq * 4 + 1][k2a] = pkh(r0.y, r1.y);
            Bt[nq * 4 + 2][k2a] = pkh(r0.z, r1.z);
            Bt[nq * 4 + 3][k2a] = pkh(r0.w, r1.w);
            Bt[nq * 4 + 0][k2b] = pkh(r2.x, r3.x);
            Bt[nq * 4 + 1][k2b] = pkh(r2.y, r3.y);
            Bt[nq * 4 + 2][k2b] = pkh(r2.z, r3.z);
            Bt[nq * 4 + 3][k2b] = pkh(r2.w, r3.w);
        }
        __syncthreads();
        #pragma unroll
        for (int hs = 0; hs < 2; ++hs) {
            const int kw = kg + hs * 32;
            h8 bf = *reinterpret_cast<const h8*>(
                      reinterpret_cast<const _Float16*>(&Bt[16 * w + ar][0]) + hs * 32 + ko8);
            #pragma unroll
            for (int mt = 0; mt < 4; ++mt) {
                h8 af = *reinterpret_cast<const h8*>(
                          SDh + (size_t)(mt * 16 + ar) * 32768 + kw + ko8);
                acc[mt] = __builtin_amdgcn_mfma_f32_16x16x32_f16(af, bf, acc[mt], 0, 0, 0);
            }
        }
        __syncthreads();
    }
    #pragma unroll
    for (int mt = 0; mt < 4; ++mt) {
        #pragma unroll
        for (int r = 0; r < 4; ++r) {
            P[(size_t)(kc * 64 + mt * 16 + (l >> 4) * 4 + r) * 4096 + n0 + 16 * w + ar] = acc[mt][r];
        }
    }
}

// ---------------- reduce partials + bias + Z2 ----------------
__global__ __launch_bounds__(256) void reduce_z2(
    const float* __restrict__ P,
    const float* __restrict__ db,
    const float* __restrict__ X,
    const float* __restrict__ fw,
    const float* __restrict__ fbp,
    float* __restrict__ out)
{
    const int o4 = blockIdx.x * 256 + threadIdx.x;   // 0..65535
    const int b  = o4 >> 10;
    const int j4 = o4 & 1023;
    const int j0 = j4 * 4;
    const int i  = j0 >> 5;
    const int m  = j0 & 31;

    float4 acc = *reinterpret_cast<const float4*>(db + j0);
    #pragma unroll
    for (int kc = 0; kc < 8; ++kc) {
        float4 p = *reinterpret_cast<const float4*>(P + (size_t)(kc * 64 + b) * 4096 + j0);
        acc.x += p.x; acc.y += p.y; acc.z += p.z; acc.w += p.w;
    }

    const float* xp = X + ((size_t)(b * 129 + 1 + i) * 128) * 32 + m;
    #pragma unroll 8
    for (int s = 0; s < 128; ++s) {
        float4 xv = *reinterpret_cast<const float4*>(xp + (size_t)s * 32);
        float w = fw[s];
        acc.x += w * xv.x; acc.y += w * xv.y; acc.z += w * xv.z; acc.w += w * xv.w;
    }
    const float fb = fbp[0];
    acc.x += fb; acc.y += fb; acc.z += fb; acc.w += fb;
    *reinterpret_cast<float4*>(out + (size_t)o4 * 4) = acc;
}

extern "C" void kernel_launch(void* const* d_in, const int* in_sizes, int n_in,
                              void* d_out, int out_size, void* d_ws, size_t ws_size,
                              hipStream_t stream) {
    const float* X    = (const float*)d_in[0];
    const float* e_k  = (const float*)d_in[1];
    const float* e_rk = (const float*)d_in[2];
    const float* e_k2 = (const float*)d_in[3];
    const float* e_b  = (const float*)d_in[4];
    const float* e_b2 = (const float*)d_in[5];
    const float* e_s0 = (const float*)d_in[6];
    const float* d_k  = (const float*)d_in[7];
    const float* d_rk = (const float*)d_in[8];
    const float* d_k2 = (const float*)d_in[9];
    const float* d_b  = (const float*)d_in[10];
    const float* d_b2 = (const float*)d_in[11];
    const float* d_s0 = (const float*)d_in[12];
    const float* dw   = (const float*)d_in[13];
    const float* db   = (const float*)d_in[14];
    const float* fw   = (const float*)d_in[15];
    const float* fb   = (const float*)d_in[16];

    float* ws = (float*)d_ws;
    // rk4e 0 | rk4d 262144 | dk4 524288 | ek4 786432 | kh2e 819200 | kh2d 851968
    // EX 884736 (+327680) | flags 1212416 | xW 1310720 (8M; reused: P 2M @1310720,
    // SDh 1M-floats @5505024 — xW dead after rec9-dec) | SE 9699328 (2M) | SD 11796480 (2M)
    float4*   rk4e  = (float4*)(ws);
    float4*   rk4d  = (float4*)(ws + 262144);
    float4*   dk4   = (float4*)(ws + 524288);
    float4*   ek4   = (float4*)(ws + 786432);
    unsigned* kh2e  = (unsigned*)(ws + 819200);
    unsigned* kh2d  = (unsigned*)(ws + 851968);
    float*    EX    = ws + 884736;
    unsigned* flags = (unsigned*)(ws + 1212416);
    float*    xW    = ws + 1310720;
    float*    SE    = ws + 9699328;
    float*    SD    = ws + 11796480;

    float*     P   = xW;                          // 8*64*4096 = 2M floats
    _Float16*  SDh = (_Float16*)(ws + 5505024);   // 2M halfs

    hipLaunchKernelGGL(packall, dim3(929), dim3(256), 0, stream,
                       e_rk, d_rk, d_k, e_k, e_k2, d_k2,
                       rk4e, rk4d, dk4, ek4, kh2e, kh2d, flags);
    hipLaunchKernelGGL(xw_gemm_enc, dim3(512), dim3(256), 0, stream,
                       X, ek4, e_b, (float4*)xW);
    hipLaunchKernelGGL(rec9, dim3(256), dim3(1024), 0, stream,
                       (const float4*)xW, rk4e, kh2e, e_b2, e_s0, SE, EX, flags, 0u);
    hipLaunchKernelGGL(xw_gemm_dec, dim3(256), dim3(512), 0, stream,
                       SE, dk4, d_b, (float4*)xW);
    hipLaunchKernelGGL(rec9, dim3(256), dim3(1024), 0, stream,
                       (const float4*)xW, rk4d, kh2d, d_b2, d_s0, SD, EX, flags, 128u);
    hipLaunchKernelGGL(cvt_sd, dim3(1024), dim3(256), 0, stream, SD, SDh);
    hipLaunchKernelGGL(mfma_dense, dim3(512), dim3(256), 0, stream, SDh, dw, P);
    hipLaunchKernelGGL(reduce_z2, dim3(256), dim3(256), 0, stream,
                       P, db, X, fw, fb, (float*)d_out);
}

// Round 22
// 1054.454 us; speedup vs baseline: 1.1720x; 1.0391x over previous
//
#include <hip/hip_runtime.h>
#include <hip/hip_fp16.h>

// B=64, T=128, U=256, D_in=32, SKIP=4; dense: (64 x 32768) @ (32768 x 4096)

typedef _Float16 h8 __attribute__((ext_vector_type(8)));
typedef float f4v __attribute__((ext_vector_type(4)));

__device__ __forceinline__ float sigmoidf_(float x) {
    return 1.0f / (1.0f + __expf(-x));
}
__device__ __forceinline__ float tanhf_(float x) {
    float xc = fminf(fmaxf(x, -15.f), 15.f);
    float e = __expf(2.f * xc);
    return (e - 1.f) / (e + 1.f);
}
__device__ __forceinline__ unsigned pkh(float lo, float hi) {
    __half2 h = __halves2half2(__float2half(lo), __float2half(hi));
    return *reinterpret_cast<unsigned*>(&h);
}
__device__ __forceinline__ float2 uph(unsigned u) {
    __half2 h = *reinterpret_cast<__half2*>(&u);
    return __half22float2(h);
}

// ---------------- all weight packing + flag zeroing ----------------
__global__ __launch_bounds__(256) void packall(
    const float* __restrict__ e_rk, const float* __restrict__ d_rk,
    const float* __restrict__ d_k,  const float* __restrict__ e_k,
    const float* __restrict__ e_k2, const float* __restrict__ d_k2,
    float4* __restrict__ rk4e, float4* __restrict__ rk4d,
    float4* __restrict__ dk4,  float4* __restrict__ ek4,
    unsigned* __restrict__ kh2e, unsigned* __restrict__ kh2d,
    unsigned* __restrict__ flags)
{
    const int bx = blockIdx.x, v = threadIdx.x;
    if (bx < 800) {
        const float* src; float4* dst; int row;
        if (bx < 256)      { src = e_rk; dst = rk4e; row = bx; }
        else if (bx < 512) { src = d_rk; dst = rk4d; row = bx - 256; }
        else if (bx < 768) { src = d_k;  dst = dk4;  row = bx - 512; }
        else               { src = e_k;  dst = ek4;  row = bx - 768; }
        const float* s = src + (size_t)row * 1024;
        dst[row * 256 + v] = make_float4(s[v], s[256 + v], s[512 + v], s[768 + v]);
    } else if (bx < 928) {
        const int u2 = bx - 800;   // 0..127
        kh2e[u2 * 256 + v] = pkh(e_k2[(2 * u2) * 256 + v], e_k2[(2 * u2 + 1) * 256 + v]);
        kh2d[u2 * 256 + v] = pkh(d_k2[(2 * u2) * 256 + v], d_k2[(2 * u2 + 1) * 256 + v]);
    } else {
        flags[v] = 0u;             // re-zeroed every launch (graph-safe)
    }
}

// ---------------- enc xW GEMM: K=32 rows gathered from X[:,0] ----------------
__global__ __launch_bounds__(256) void xw_gemm_enc(
    const float*  __restrict__ X,
    const float4* __restrict__ ek4,
    const float*  __restrict__ bias,
    float4* __restrict__ xWp)
{
    const int v = threadIdx.x;
    const int r0 = blockIdx.x * 16;
    __shared__ float se[16][32];

    #pragma unroll
    for (int p = 0; p < 2; ++p) {
        int idx = p * 256 + v;
        int rr = idx >> 5, d = idx & 31;
        int R = r0 + rr, b = R >> 7, t = R & 127;
        se[rr][d] = X[((size_t)b * 129 * 128 + t) * 32 + d];   // X[b,0,t,d]
    }
    __syncthreads();

    float4 bv = make_float4(bias[v], bias[256 + v], bias[512 + v], bias[768 + v]);
    float4 acc[16];
    #pragma unroll
    for (int rr = 0; rr < 16; ++rr) acc[rr] = bv;

    #pragma unroll
    for (int u = 0; u < 32; ++u) {
        float4 w = ek4[u * 256 + v];
        #pragma unroll
        for (int rr = 0; rr < 16; ++rr) {
            float s = se[rr][u];
            acc[rr].x += s * w.x; acc[rr].y += s * w.y;
            acc[rr].z += s * w.z; acc[rr].w += s * w.w;
        }
    }
    #pragma unroll
    for (int rr = 0; rr < 16; ++rr)
        xWp[(size_t)(r0 + rr) * 256 + v] = acc[rr];
}

// ---------------- dec xW GEMM: 32 rows/block, 512 threads ----------------
__global__ __launch_bounds__(512) void xw_gemm_dec(
    const float*  __restrict__ SE,
    const float4* __restrict__ dk4,
    const float*  __restrict__ bias,
    float4* __restrict__ xWp)
{
    const int tid = threadIdx.x;
    const int v = tid & 255;
    const int hh = tid >> 8;               // 0/1
    const int rbase = blockIdx.x * 32;
    __shared__ float se[32][256];

    for (int i = tid; i < 8192; i += 512) {
        int rr = i >> 8, c = i & 255;
        se[rr][c] = SE[(size_t)(rbase + rr) * 256 + c];
    }
    __syncthreads();

    float4 bv = make_float4(bias[v], bias[256 + v], bias[512 + v], bias[768 + v]);
    float4 acc[16];
    #pragma unroll
    for (int rr = 0; rr < 16; ++rr) acc[rr] = bv;

    #pragma unroll 8
    for (int u = 0; u < 256; ++u) {
        float4 w = dk4[u * 256 + v];
        #pragma unroll
        for (int rr = 0; rr < 16; ++rr) {
            float s = se[hh * 16 + rr][u];
            acc[rr].x += s * w.x; acc[rr].y += s * w.y;
            acc[rr].z += s * w.z; acc[rr].w += s * w.w;
        }
    }
    #pragma unroll
    for (int rr = 0; rr < 16; ++rr)
        xWp[(size_t)(rbase + hh * 16 + rr) * 256 + v] = acc[rr];
}

// ---------------- skip-LSTM recurrence (rec9 structure; optional fp16 output) ----------------
__global__ __launch_bounds__(1024, 4) void rec9(
    const float4*   __restrict__ xW,
    const float4*   __restrict__ rk4,
    const unsigned* __restrict__ kh2,
    const float*    __restrict__ bias2,
    const float*    __restrict__ s0p,
    float* __restrict__ out,            // fp32 output (used when outh == nullptr)
    _Float16* __restrict__ outh,        // fp16 output (dec: feeds MFMA dense directly)
    float* __restrict__ EX,             // [2][64][4][320] floats
    unsigned* __restrict__ flags,       // [64][4]
    unsigned fbase)
{
    const int b     = blockIdx.x & 63;
    const int slice = blockIdx.x >> 6;
    const int voff  = slice * 64;
    const int tid   = threadIdx.x;
    const int us    = tid >> 6;
    const int vl    = tid & 63;
    const int v     = voff + vl;

    __shared__ float4 wres[128][64];
    __shared__ float4 pA[16][64];
    __shared__ float  pS[16][64];
    __shared__ float4 h4[256];
    __shared__ float  pq[4][256];

    for (int i = tid; i < 8192; i += 1024) {
        int r = i >> 6, vv = i & 63;
        int cc = r >> 3, j = r & 7;
        wres[r][vv] = rk4[(cc * 16 + j) * 256 + voff + vv];
    }
    float4 wreg[8];
    unsigned kreg[8];
    {
        const float4*   wp = rk4 + (us * 16 + 8) * 256 + v;
        const unsigned* kp = kh2 + (us * 8) * 256 + v;
        #pragma unroll
        for (int j = 0; j < 8; ++j) wreg[j] = wp[j * 256];
        #pragma unroll
        for (int j = 0; j < 8; ++j) kreg[j] = kp[j * 256];
    }
    if (tid < 256) {
        h4[tid] = make_float4(0.f, 0.f, 0.f, 0.f);
        pq[0][tid] = 0.f; pq[1][tid] = 0.f; pq[2][tid] = 0.f; pq[3][tid] = 0.f;
    }
    float cst = 0.f;
    const float s0 = s0p[0];
    const float b2 = bias2[voff + vl];
    unsigned* mflag = flags + b * 4 + slice;
    __syncthreads();

    for (int t = 0; t < 128; ++t) {
        float4 xa = make_float4(0.f, 0.f, 0.f, 0.f);
        if (tid < 64) xa = xW[((size_t)b * 128 + t) * 256 + voff + tid];
        if (t > 0 && tid < 3) {
            int ps = tid + (tid >= slice ? 1 : 0);
            const unsigned* pf = flags + b * 4 + ps;
            while (__hip_atomic_load(pf, __ATOMIC_RELAXED, __HIP_MEMORY_SCOPE_AGENT) < fbase + (unsigned)t)
                __builtin_amdgcn_s_sleep(2);
        }
        __syncthreads();
        if (t > 0) {
            const int sp = (t + 1) & 1;
            if (tid < 480) {
                int pi = tid / 160;
                int j  = tid - pi * 160;
                int ps = pi + (pi >= slice ? 1 : 0);
                const unsigned long long* src = (const unsigned long long*)
                    (EX + (((size_t)sp * 64 + b) * 4 + ps) * 320);
                unsigned long long d = __hip_atomic_load(src + j, __ATOMIC_RELAXED, __HIP_MEMORY_SCOPE_AGENT);
                if (j < 128) {
                    reinterpret_cast<unsigned long long*>(&h4[ps * 64])[j] = d;
                } else {
                    int k = j - 128;
                    union { unsigned long long u; float f[2]; } cv; cv.u = d;
                    pq[(t + 3) & 3][ps * 64 + 2 * k]     = cv.f[0];
                    pq[(t + 3) & 3][ps * 64 + 2 * k + 1] = cv.f[1];
                }
            }
        }
        __syncthreads();

        float ai = 0.f, af = 0.f, acg = 0.f, ao = 0.f, as = 0.f;
        const int slot = t & 3;
        #pragma unroll
        for (int j = 0; j < 8; ++j) {
            float4 w = wres[us * 8 + j][vl];
            float4 g = h4[us * 16 + j];
            ai += g.x * w.x; af += g.y * w.y; acg += g.z * w.z; ao += g.w * w.w;
        }
        #pragma unroll
        for (int j = 0; j < 8; ++j) {
            float4 w = wreg[j];
            float4 g = h4[us * 16 + 8 + j];
            ai += g.x * w.x; af += g.y * w.y; acg += g.z * w.z; ao += g.w * w.w;
        }
        #pragma unroll
        for (int j = 0; j < 8; ++j) {
            float2 kk = uph(kreg[j]);
            as += pq[slot][us * 16 + 2 * j] * kk.x + pq[slot][us * 16 + 2 * j + 1] * kk.y;
        }
        pA[us][vl] = make_float4(ai, af, acg, ao);
        pS[us][vl] = as;
        __syncthreads();

        if (tid < 64) {
            float4 A = pA[0][vl];
            float  S = pS[0][vl];
            #pragma unroll
            for (int cc = 1; cc < 16; ++cc) {
                float4 q = pA[cc][vl];
                A.x += q.x; A.y += q.y; A.z += q.z; A.w += q.w;
                S += pS[cc][vl];
            }
            float gi = sigmoidf_(xa.x + A.x);
            float gf = sigmoidf_(xa.y + A.y);
            float cb = tanhf_(xa.z + A.z);
            cst = gf * cst + gi * cb;
            float go = sigmoidf_(xa.w + A.w);
            float hh = go * tanhf_(cst);
            float hs = sigmoidf_(S + b2);
            float hf = s0 * hh + (1.f - s0) * hs;
            h4[voff + vl] = make_float4(gi, gf, cst, go);
            pq[slot][voff + vl] = hf;
            if (outh) outh[((size_t)b * 128 + t) * 256 + voff + vl] = (_Float16)hf;
            else      out [((size_t)b * 128 + t) * 256 + voff + vl] = hf;
            float* dst = EX + (((size_t)(t & 1) * 64 + b) * 4 + slice) * 320;
            union { float4 f4; unsigned long long u[2]; } gv;
            gv.f4 = make_float4(gi, gf, cst, go);
            __hip_atomic_store((unsigned long long*)dst + 2 * vl,     gv.u[0], __ATOMIC_RELAXED, __HIP_MEMORY_SCOPE_AGENT);
            __hip_atomic_store((unsigned long long*)dst + 2 * vl + 1, gv.u[1], __ATOMIC_RELAXED, __HIP_MEMORY_SCOPE_AGENT);
            __hip_atomic_store(dst + 256 + vl, hf, __ATOMIC_RELAXED, __HIP_MEMORY_SCOPE_AGENT);
        }
        __syncthreads();
        if (tid == 0)
            __hip_atomic_store(mflag, fbase + (unsigned)(t + 1), __ATOMIC_RELAXED, __HIP_MEMORY_SCOPE_AGENT);
    }
}

// ---------------- dense via MFMA fp16: split-K 16 (1024 blocks, 4/CU) ----------------
// grid 1024: kc = bid>>6 (0..15, 2048 k-rows each), nb = bid&63. Block 256 thr = 4 waves.
__global__ __launch_bounds__(256, 4) void mfma_dense(
    const _Float16* __restrict__ SDh,   // (64 x 32768)
    const float*    __restrict__ dw,    // (32768 x 4096)
    float* __restrict__ P)              // (16 x 64 x 4096)
{
    const int nb  = blockIdx.x & 63;
    const int kc  = blockIdx.x >> 6;    // 0..15
    const int n0  = nb * 64;
    const int tid = threadIdx.x;
    const int w   = tid >> 6;           // wave 0..3
    const int l   = tid & 63;
    const int ar  = l & 15;
    const int ko8 = (l >> 4) * 8;       // k-offset (halfs) within a 32-k window
    const int rq  = tid >> 4;           // 0..15 row-quad
    const int nq  = tid & 15;           // 0..15 n-quad

    __shared__ unsigned Bt[64][36];     // [n][k2] half2-packed (32 k2 + pad)

    f4v acc[4] = {{0.f,0.f,0.f,0.f},{0.f,0.f,0.f,0.f},{0.f,0.f,0.f,0.f},{0.f,0.f,0.f,0.f}};

    for (int kk = 0; kk < 32; ++kk) {
        const int kg = kc * 2048 + kk * 64;
        // stage 64k x 64n panel: 4 float4 loads per thread, pack row-pairs
        {
            const float* base = dw + (size_t)(kg + rq * 4) * 4096 + n0 + nq * 4;
            float4 r0 = *reinterpret_cast<const float4*>(base);
            float4 r1 = *reinterpret_cast<const float4*>(base + 4096);
            float4 r2 = *reinterpret_cast<const float4*>(base + 2 * 4096);
            float4 r3 = *reinterpret_cast<const float4*>(base + 3 * 4096);
            const int k2a = rq * 2, k2b = rq * 2 + 1;
            Bt[nq * 4 + 0][k2a] = pkh(r0.x, r1.x);
            Bt[nq * 4 + 1][k2a] = pkh(r0.y, r1.y);
            Bt[nq * 4 + 2][k2a] = pkh(r0.z, r1.z);
            Bt[nq * 4 + 3][k2a] = pkh(r0.w, r1.w);
            Bt[nq * 4 + 0][k2b] = pkh(r2.x, r3.x);
            Bt[nq * 4 + 1][k2b] = pkh(r2.y, r3.y);
            Bt[nq * 4 + 2][k2b] = pkh(r2.z, r3.z);
            Bt[nq * 4 + 3][k2b] = pkh(r2.w, r3.w);
        }
        __syncthreads();
        #pragma unroll
        for (int hs = 0; hs < 2; ++hs) {
            const int kw = kg + hs * 32;
            h8 bf = *reinterpret_cast<const h8*>(
                      reinterpret_cast<const _Float16*>(&Bt[16 * w + ar][0]) + hs * 32 + ko8);
            #pragma unroll
            for (int mt = 0; mt < 4; ++mt) {
                h8 af = *reinterpret_cast<const h8*>(
                          SDh + (size_t)(mt * 16 + ar) * 32768 + kw + ko8);
                acc[mt] = __builtin_amdgcn_mfma_f32_16x16x32_f16(af, bf, acc[mt], 0, 0, 0);
            }
        }
        __syncthreads();
    }
    #pragma unroll
    for (int mt = 0; mt < 4; ++mt) {
        #pragma unroll
        for (int r = 0; r < 4; ++r) {
            P[(size_t)(kc * 64 + mt * 16 + (l >> 4) * 4 + r) * 4096 + n0 + 16 * w + ar] = acc[mt][r];
        }
    }
}

// ---------------- reduce partials + bias + Z2 ----------------
__global__ __launch_bounds__(256) void reduce_z2(
    const float* __restrict__ P,
    const float* __restrict__ db,
    const float* __restrict__ X,
    const float* __restrict__ fw,
    const float* __restrict__ fbp,
    float* __restrict__ out)
{
    const int o4 = blockIdx.x * 256 + threadIdx.x;   // 0..65535
    const int b  = o4 >> 10;
    const int j4 = o4 & 1023;
    const int j0 = j4 * 4;
    const int i  = j0 >> 5;
    const int m  = j0 & 31;

    float4 acc = *reinterpret_cast<const float4*>(db + j0);
    #pragma unroll
    for (int kc = 0; kc < 16; ++kc) {
        float4 p = *reinterpret_cast<const float4*>(P + (size_t)(kc * 64 + b) * 4096 + j0);
        acc.x += p.x; acc.y += p.y; acc.z += p.z; acc.w += p.w;
    }

    const float* xp = X + ((size_t)(b * 129 + 1 + i) * 128) * 32 + m;
    #pragma unroll 8
    for (int s = 0; s < 128; ++s) {
        float4 xv = *reinterpret_cast<const float4*>(xp + (size_t)s * 32);
        float w = fw[s];
        acc.x += w * xv.x; acc.y += w * xv.y; acc.z += w * xv.z; acc.w += w * xv.w;
    }
    const float fb = fbp[0];
    acc.x += fb; acc.y += fb; acc.z += fb; acc.w += fb;
    *reinterpret_cast<float4*>(out + (size_t)o4 * 4) = acc;
}

extern "C" void kernel_launch(void* const* d_in, const int* in_sizes, int n_in,
                              void* d_out, int out_size, void* d_ws, size_t ws_size,
                              hipStream_t stream) {
    const float* X    = (const float*)d_in[0];
    const float* e_k  = (const float*)d_in[1];
    const float* e_rk = (const float*)d_in[2];
    const float* e_k2 = (const float*)d_in[3];
    const float* e_b  = (const float*)d_in[4];
    const float* e_b2 = (const float*)d_in[5];
    const float* e_s0 = (const float*)d_in[6];
    const float* d_k  = (const float*)d_in[7];
    const float* d_rk = (const float*)d_in[8];
    const float* d_k2 = (const float*)d_in[9];
    const float* d_b  = (const float*)d_in[10];
    const float* d_b2 = (const float*)d_in[11];
    const float* d_s0 = (const float*)d_in[12];
    const float* dw   = (const float*)d_in[13];
    const float* db   = (const float*)d_in[14];
    const float* fw   = (const float*)d_in[15];
    const float* fb   = (const float*)d_in[16];

    float* ws = (float*)d_ws;
    // rk4e 0 | rk4d 262144 | dk4 524288 | ek4 786432 | kh2e 819200 | kh2d 851968
    // EX 884736 (+327680) | flags 1212416 | xW 1310720 (8M; reused as P 4M after rec-dec)
    // SE 9699328 (2M) | SDh 11796480 (2M halfs = 1M floats)
    float4*   rk4e  = (float4*)(ws);
    float4*   rk4d  = (float4*)(ws + 262144);
    float4*   dk4   = (float4*)(ws + 524288);
    float4*   ek4   = (float4*)(ws + 786432);
    unsigned* kh2e  = (unsigned*)(ws + 819200);
    unsigned* kh2d  = (unsigned*)(ws + 851968);
    float*    EX    = ws + 884736;
    unsigned* flags = (unsigned*)(ws + 1212416);
    float*    xW    = ws + 1310720;
    float*    SE    = ws + 9699328;
    _Float16* SDh   = (_Float16*)(ws + 11796480);

    float* P = xW;   // 16*64*4096 = 4M floats; xW dead after rec9-dec

    hipLaunchKernelGGL(packall, dim3(929), dim3(256), 0, stream,
                       e_rk, d_rk, d_k, e_k, e_k2, d_k2,
                       rk4e, rk4d, dk4, ek4, kh2e, kh2d, flags);
    hipLaunchKernelGGL(xw_gemm_enc, dim3(512), dim3(256), 0, stream,
                       X, ek4, e_b, (float4*)xW);
    hipLaunchKernelGGL(rec9, dim3(256), dim3(1024), 0, stream,
                       (const float4*)xW, rk4e, kh2e, e_b2, e_s0, SE, (_Float16*)nullptr,
                       EX, flags, 0u);
    hipLaunchKernelGGL(xw_gemm_dec, dim3(256), dim3(512), 0, stream,
                       SE, dk4, d_b, (float4*)xW);
    hipLaunchKernelGGL(rec9, dim3(256), dim3(1024), 0, stream,
                       (const float4*)xW, rk4d, kh2d, d_b2, d_s0, (float*)nullptr, SDh,
                       EX, flags, 128u);
    hipLaunchKernelGGL(mfma_dense, dim3(1024), dim3(256), 0, stream, SDh, dw, P);
    hipLaunchKernelGGL(reduce_z2, dim3(256), dim3(256), 0, stream,
                       P, db, X, fw, fb, (float*)d_out);
}